// Round 1
// 350.613 us; speedup vs baseline: 1.2665x; 1.2665x over previous
//
#include <hip/hip_runtime.h>
#include <math.h>

static constexpr int Bn = 8;
static constexpr int Cn = 256;
static constexpr int Sn = 16384;   // 128*128

typedef __bf16 bf16x4 __attribute__((ext_vector_type(4)));
typedef __bf16 bf16x8 __attribute__((ext_vector_type(8)));
typedef float  f32x4  __attribute__((ext_vector_type(4)));

// ---------------- Kernel 1: partial Gram (energy) via split-bf16 MFMA -------
// energy[b][c][d] = sum_s v[b,c,s] * v[b,d,s]
// x = hi + lo (bf16 split); energy ~= hi.hi^T + hi.lo^T + lo.hi^T (fp32 acc).
// Block tile 128x128 over (c,d); K split into 16 slices of 1024; LDS chunks of 32.
static constexpr int TILE   = 128;
static constexpr int KSPLIT = 16;
static constexpr int KSLICE = Sn / KSPLIT;  // 1024
static constexpr int KB     = 32;
static constexpr int LP     = 56;           // LDS row stride in bf16 (112 B: 16B-aligned, conflict-free partition)

__global__ __launch_bounds__(256, 2) void gram_kernel(const float* __restrict__ x,
                                                      float* __restrict__ energy) {
  const int b   = blockIdx.z;
  const int tij = blockIdx.y;             // 0..3 -> (ti,tj) in 2x2
  const int ti  = tij >> 1, tj = tij & 1;
  const int kk  = blockIdx.x;             // k-slice

  const float* vb    = x + (size_t)b * Cn * Sn;
  const float* Abase = vb + (size_t)(ti * TILE) * Sn + kk * KSLICE;
  const float* Bbase = vb + (size_t)(tj * TILE) * Sn + kk * KSLICE;

  __shared__ __align__(16) __bf16 Ah[TILE * LP];
  __shared__ __align__(16) __bf16 Al[TILE * LP];
  __shared__ __align__(16) __bf16 Bh[TILE * LP];
  __shared__ __align__(16) __bf16 Bl[TILE * LP];

  const int t    = threadIdx.x;           // 0..255
  const int lane = t & 63;
  const int wv   = t >> 6;                // wave 0..3
  const int wr   = wv >> 1;               // wave row (c) in 2x2 of 64x64
  const int wc   = wv & 1;                // wave col (d)
  const int ln   = lane & 15;
  const int quad = lane >> 4;             // 0..3

  f32x4 acc[4][4];
#pragma unroll
  for (int i = 0; i < 4; i++)
#pragma unroll
    for (int j = 0; j < 4; j++) acc[i][j] = (f32x4){0.f, 0.f, 0.f, 0.f};

  for (int kc = 0; kc < KSLICE; kc += KB) {
    // stage 128 rows x 32 k, fp32 -> (hi,lo) bf16 into LDS
#pragma unroll
    for (int it = 0; it < 4; it++) {
      int idx = t + it * 256;             // 0..1023
      int row = idx >> 3;                 // 0..127
      int kq  = idx & 7;                  // float4 index within 32
      float4 av = *(const float4*)(Abase + (size_t)row * Sn + kc + kq * 4);
      float4 bv = *(const float4*)(Bbase + (size_t)row * Sn + kc + kq * 4);
      bf16x4 ah, al4, bh, bl4;
      {
        __bf16 h0 = (__bf16)av.x, h1 = (__bf16)av.y, h2 = (__bf16)av.z, h3 = (__bf16)av.w;
        ah  = (bf16x4){h0, h1, h2, h3};
        al4 = (bf16x4){(__bf16)(av.x - (float)h0), (__bf16)(av.y - (float)h1),
                       (__bf16)(av.z - (float)h2), (__bf16)(av.w - (float)h3)};
      }
      {
        __bf16 h0 = (__bf16)bv.x, h1 = (__bf16)bv.y, h2 = (__bf16)bv.z, h3 = (__bf16)bv.w;
        bh  = (bf16x4){h0, h1, h2, h3};
        bl4 = (bf16x4){(__bf16)(bv.x - (float)h0), (__bf16)(bv.y - (float)h1),
                       (__bf16)(bv.z - (float)h2), (__bf16)(bv.w - (float)h3)};
      }
      *(bf16x4*)&Ah[row * LP + kq * 4] = ah;
      *(bf16x4*)&Al[row * LP + kq * 4] = al4;
      *(bf16x4*)&Bh[row * LP + kq * 4] = bh;
      *(bf16x4*)&Bl[row * LP + kq * 4] = bl4;
    }
    __syncthreads();

    // frags: A rows wr*64 + i*16 + ln; B rows wc*64 + j*16 + ln; k = quad*8..+7
    bf16x8 fah[4], fal[4], fbh[4], fbl[4];
#pragma unroll
    for (int i = 0; i < 4; i++) {
      int ar = wr * 64 + i * 16 + ln;
      int br = wc * 64 + i * 16 + ln;
      fah[i] = *(const bf16x8*)&Ah[ar * LP + quad * 8];
      fal[i] = *(const bf16x8*)&Al[ar * LP + quad * 8];
      fbh[i] = *(const bf16x8*)&Bh[br * LP + quad * 8];
      fbl[i] = *(const bf16x8*)&Bl[br * LP + quad * 8];
    }
#pragma unroll
    for (int i = 0; i < 4; i++)
#pragma unroll
      for (int j = 0; j < 4; j++) {
        acc[i][j] = __builtin_amdgcn_mfma_f32_16x16x32_bf16(fah[i], fbh[j], acc[i][j], 0, 0, 0);
        acc[i][j] = __builtin_amdgcn_mfma_f32_16x16x32_bf16(fah[i], fbl[j], acc[i][j], 0, 0, 0);
        acc[i][j] = __builtin_amdgcn_mfma_f32_16x16x32_bf16(fal[i], fbh[j], acc[i][j], 0, 0, 0);
      }
    __syncthreads();
  }

  // epilogue: C/D layout col=lane&15, row=quad*4+reg (m89-verified)
  float* eb = energy + ((size_t)b * Cn + ti * TILE) * Cn + tj * TILE;
#pragma unroll
  for (int i = 0; i < 4; i++)
#pragma unroll
    for (int j = 0; j < 4; j++) {
      int c0 = wr * 64 + i * 16 + quad * 4;
      int d  = wc * 64 + j * 16 + ln;
#pragma unroll
      for (int r = 0; r < 4; r++)
        atomicAdd(&eb[(size_t)(c0 + r) * Cn + d], acc[i][j][r]);
    }
}

// ---------------- Kernel 2: reduce + softmax ----------------
// softmax(max_d(e) - e) over d  ==  exp(e_min - e_d) / sum  (row max cancels)
__global__ __launch_bounds__(256) void softmax_kernel(float* __restrict__ energy) {
  const int row = blockIdx.x;          // b*Cn + c
  const int t   = threadIdx.x;
  float e = energy[(size_t)row * Cn + t];

  __shared__ float red[256];
  red[t] = e;
  __syncthreads();
  for (int s = 128; s > 0; s >>= 1) {
    if (t < s) red[t] = fminf(red[t], red[t + s]);
    __syncthreads();
  }
  float emin = red[0];
  __syncthreads();

  float p = expf(emin - e);
  red[t] = p;
  __syncthreads();
  for (int s = 128; s > 0; s >>= 1) {
    if (t < s) red[t] += red[t + s];
    __syncthreads();
  }
  float inv = 1.f / red[0];
  energy[(size_t)row * Cn + t] = p * inv;   // in-place: energy becomes w
}

// ---------------- Kernel 3: y = w @ v via split-bf16 MFMA, out = alpha*y + x -
// A = w[b] (256x256 fp32, k contiguous). B = v[b] (256x16384, k is the SLOW
// axis -> stage transposed into LDS via per-lane k-column loads).
// Block tile 128(M) x 128(N); 4 waves in 2x2, each 64x64 (4x4 frags of 16x16).
// K = 256 in chunks of 32 -> acc stays in registers, single pass, no atomics.
static constexpr int LPY = 40;   // LDS row stride bf16 (80 B: 16B-aligned; frag
                                 // reads & staging writes both at bank floor)

__global__ __launch_bounds__(256, 2) void ygemm_mfma_kernel(const float* __restrict__ w,
                                                            const float* __restrict__ x,
                                                            const float* __restrict__ alpha,
                                                            float* __restrict__ out) {
  const int b  = blockIdx.z;
  const int m0 = blockIdx.y * 128;        // output row tile (c)
  const int s0 = blockIdx.x * 128;        // output col tile (s)

  const float* Wb = w + ((size_t)b * Cn + m0) * Cn;   // w rows, k contiguous
  const float* Vb = x + (size_t)b * Cn * Sn;          // v rows [k][s]

  __shared__ __align__(16) __bf16 Ah[128 * LPY];
  __shared__ __align__(16) __bf16 Al[128 * LPY];
  __shared__ __align__(16) __bf16 Bh[128 * LPY];      // transposed: [s][k]
  __shared__ __align__(16) __bf16 Bl[128 * LPY];

  const int t    = threadIdx.x;
  const int lane = t & 63;
  const int wv   = t >> 6;
  const int wr   = wv >> 1;               // wave row (m)
  const int wc   = wv & 1;                // wave col (s)
  const int ln   = lane & 15;
  const int quad = lane >> 4;

  const int kq8 = t & 7;                  // B staging: k-quad 0..7
  const int sr0 = t >> 3;                 // B staging: s row 0..31

  f32x4 acc[4][4];
#pragma unroll
  for (int i = 0; i < 4; i++)
#pragma unroll
    for (int j = 0; j < 4; j++) acc[i][j] = (f32x4){0.f, 0.f, 0.f, 0.f};

  for (int kc = 0; kc < Cn; kc += KB) {
    // ---- A staging: 128 m-rows x 32 k, contiguous-k float4 loads (L2-hot) ----
#pragma unroll
    for (int it = 0; it < 4; it++) {
      int idx = t + it * 256;             // 0..1023
      int row = idx >> 3;                 // 0..127
      int kq  = idx & 7;
      float4 av = *(const float4*)(Wb + (size_t)row * Cn + kc + kq * 4);
      __bf16 h0 = (__bf16)av.x, h1 = (__bf16)av.y, h2 = (__bf16)av.z, h3 = (__bf16)av.w;
      *(bf16x4*)&Ah[row * LPY + kq * 4] = (bf16x4){h0, h1, h2, h3};
      *(bf16x4*)&Al[row * LPY + kq * 4] = (bf16x4){(__bf16)(av.x - (float)h0),
                                                   (__bf16)(av.y - (float)h1),
                                                   (__bf16)(av.z - (float)h2),
                                                   (__bf16)(av.w - (float)h3)};
    }
    // ---- B staging (transpose): lane = (kq8, s); 4 strided-row dword loads,
    //      each instruction reads 8 rows x 128 B contiguous (coalesced);
    //      LDS write = bf16x4 at [s][kq8*4] -> 8 lanes x 64 B/row (bank floor).
#pragma unroll
    for (int it = 0; it < 4; it++) {
      int s = sr0 + it * 32;              // 0..127
      const float* col = Vb + (size_t)(kc + kq8 * 4) * Sn + s0 + s;
      float e0 = col[0];
      float e1 = col[(size_t)Sn];
      float e2 = col[(size_t)2 * Sn];
      float e3 = col[(size_t)3 * Sn];
      __bf16 h0 = (__bf16)e0, h1 = (__bf16)e1, h2 = (__bf16)e2, h3 = (__bf16)e3;
      *(bf16x4*)&Bh[s * LPY + kq8 * 4] = (bf16x4){h0, h1, h2, h3};
      *(bf16x4*)&Bl[s * LPY + kq8 * 4] = (bf16x4){(__bf16)(e0 - (float)h0),
                                                  (__bf16)(e1 - (float)h1),
                                                  (__bf16)(e2 - (float)h2),
                                                  (__bf16)(e3 - (float)h3)};
    }
    __syncthreads();

    bf16x8 fah[4], fal[4], fbh[4], fbl[4];
#pragma unroll
    for (int i = 0; i < 4; i++) {
      int ar = wr * 64 + i * 16 + ln;     // m-row within tile
      int br = wc * 64 + i * 16 + ln;     // s-row within tile
      fah[i] = *(const bf16x8*)&Ah[ar * LPY + quad * 8];
      fal[i] = *(const bf16x8*)&Al[ar * LPY + quad * 8];
      fbh[i] = *(const bf16x8*)&Bh[br * LPY + quad * 8];
      fbl[i] = *(const bf16x8*)&Bl[br * LPY + quad * 8];
    }
#pragma unroll
    for (int i = 0; i < 4; i++)
#pragma unroll
      for (int j = 0; j < 4; j++) {
        acc[i][j] = __builtin_amdgcn_mfma_f32_16x16x32_bf16(fah[i], fbh[j], acc[i][j], 0, 0, 0);
        acc[i][j] = __builtin_amdgcn_mfma_f32_16x16x32_bf16(fah[i], fbl[j], acc[i][j], 0, 0, 0);
        acc[i][j] = __builtin_amdgcn_mfma_f32_16x16x32_bf16(fal[i], fbh[j], acc[i][j], 0, 0, 0);
      }
    __syncthreads();
  }

  // epilogue: C/D layout col=lane&15 (s side), row=quad*4+reg (m side); fuse
  // residual + alpha. Lanes within a quad store 16 consecutive dwords.
  const float al = alpha[0];
#pragma unroll
  for (int i = 0; i < 4; i++)
#pragma unroll
    for (int j = 0; j < 4; j++) {
      int c = m0 + wr * 64 + i * 16 + quad * 4;
      int s = s0 + wc * 64 + j * 16 + ln;
      const float* xr = x   + ((size_t)b * Cn + c) * Sn + s;
      float*       orp = out + ((size_t)b * Cn + c) * Sn + s;
#pragma unroll
      for (int r = 0; r < 4; r++)
        orp[(size_t)r * Sn] = al * acc[i][j][r] + xr[(size_t)r * Sn];
    }
}

extern "C" void kernel_launch(void* const* d_in, const int* in_sizes, int n_in,
                              void* d_out, int out_size, void* d_ws, size_t ws_size,
                              hipStream_t stream) {
  const float* x     = (const float*)d_in[0];
  const float* alpha = (const float*)d_in[1];
  float*       out   = (float*)d_out;
  float*       energy = (float*)d_ws;          // B*C*C fp32 = 2 MB; becomes w in-place

  const size_t energy_bytes = (size_t)Bn * Cn * Cn * sizeof(float);
  hipMemsetAsync(energy, 0, energy_bytes, stream);

  dim3 g1(KSPLIT, 4, Bn);                      // 16 x 4 x 8 = 512 blocks
  gram_kernel<<<g1, 256, 0, stream>>>(x, energy);

  softmax_kernel<<<Bn * Cn, 256, 0, stream>>>(energy);

  dim3 g3(Sn / 128, Cn / 128, Bn);             // 128 x 2 x 8 = 2048 blocks
  ygemm_mfma_kernel<<<g3, 256, 0, stream>>>(energy, x, alpha, out);
}